// Round 12
// baseline (11636.416 us; speedup 1.0000x reference)
//
#include <hip/hip_runtime.h>
#include <hip/hip_bf16.h>
#include <stdint.h>
#include <stddef.h>

#define B_SZ   4096
#define U_SZ   1024
#define SEQ    5
#define TSTEPS 200
#define STEPS  204          // 5 warmup + 199 decode LSTM steps

typedef __bf16 bf16_t;
typedef __bf16 bf16x8 __attribute__((ext_vector_type(8)));
typedef float  f32x4  __attribute__((ext_vector_type(4)));

#define AS1 __attribute__((address_space(1)))
#define AS3 __attribute__((address_space(3)))

#define LOAD_LDS16(gp, lp) \
    __builtin_amdgcn_global_load_lds((const AS1 unsigned int*)(gp), \
                                     (AS3 unsigned int*)(lp), 16, 0, 0)

__device__ __forceinline__ float fsig(float x) {
    return 1.0f / (1.0f + __expf(-x));
}
__device__ __forceinline__ float ftanh(float x) {
    x = fminf(fmaxf(x, -15.0f), 15.0f);
    float e = __expf(2.0f * x);
    return (e - 1.0f) / (e + 1.0f);
}

// ---------------------------------------------------------------------------
// Pack R (1024 x 4096 fp32 row-major) into bf16 panels, one per ub (32 u's),
// with XOR-swizzled 16B slots to kill LDS bank conflicts (round-6 verbatim).
// ---------------------------------------------------------------------------
__global__ void pack_R(const float* __restrict__ R, bf16_t* __restrict__ Rp) {
    int idx = blockIdx.x * 256 + threadIdx.x;   // 4,194,304 total
    int e    = idx & 7;
    int slot = (idx >> 3) & 7;                  // physical 16B slot in row
    int c    = (idx >> 6) & 127;
    int kb   = (idx >> 13) & 15;
    int ub   = idx >> 17;
    int g  = (c >> 4) & 3;
    int wc = c >> 6;
    int cl = c & 15;
    int n  = g * 1024 + ub * 32 + wc * 16 + cl;
    int k  = kb * 64 + ((slot ^ (c & 7)) << 3) + e;   // un-swizzle -> logical k
    Rp[idx] = (bf16_t)R[(size_t)k * 4096 + n];
}

// ---------------------------------------------------------------------------
// One LSTM step — r10 base with A REMOVED FROM LDS:
//   A-fragments load global->register directly (r9-verified addressing),
//   issued FIRST each kb so the MFMA's af-wait is vmcnt(8) and the B stage
//   (issued after) stays in flight (fixes r9's FIFO bug).
//   B double-buffered in LDS (2 x 32 KB), staged a full iteration ahead.
//   ONE __syncthreads per kb (its vmcnt(0) drains exactly stage_B(kb)).
//   2-D XCD tiling (r10-verified): xcd=bid&7 owns 4p x 16G.
// ---------------------------------------------------------------------------
__global__ __launch_bounds__(256, 2)
void lstm_step(const bf16_t* __restrict__ hin,
               bf16_t* __restrict__ hout,
               float* __restrict__ cst,
               const bf16_t* __restrict__ Rp,
               const float* __restrict__ Wx,     // (4096,)
               const float* __restrict__ bias,   // (4096,)
               const float* __restrict__ w1,     // (1024,)
               const float* __restrict__ b1,
               const float* __restrict__ w2,
               const float* __restrict__ b2,
               const float* __restrict__ inputs, // [4096,5]
               float* __restrict__ praw,         // 3*4096
               float* __restrict__ out,          // [4096,200]
               int t)
{
    __shared__ __align__(16) bf16_t lsB[2][2][8192];     // 64 KB (dbuf x 2T)
    __shared__ float lsX[128];

    const int tid  = threadIdx.x;
    const int wave = tid >> 6;
    const int lane = tid & 63;
    // ---- 2-D XCD tiling (r10-verified): xcd = bid&7 owns
    //      p in [(xcd&3)*4, +4), G in [(xcd>>2)*16, +16) ----
    const int bid  = blockIdx.x + 16 * blockIdx.y;   // x fastest (dispatch)
    const int xcd  = bid & 7;
    const int j    = bid >> 3;                       // 0..63 within XCD
    const int p    = (xcd & 3) * 4 + (j & 3);        // 0..15
    const int G    = (xcd >> 2) * 16 + (j >> 2);     // 0..31
    const int l15  = lane & 15;
    const int quad = lane >> 4;
    const int rbase = (wave >> 1) * 64;
    const int wc    = wave & 1;

    float*       pr_acc  = praw + (size_t)(t % 3) * B_SZ;
    const float* pr_read = praw + (size_t)((t + 2) % 3) * B_SZ;
    float*       pr_zero = praw + (size_t)((t + 1) % 3) * B_SZ;

    const bf16_t* Ap  = hin + (size_t)G * 128 * U_SZ;
    const bf16_t* Bp0 = Rp + (size_t)(2 * p) * 131072;
    const bf16_t* Bp1 = Bp0 + 131072;
    // A fragment base (r9-verified): lane reads 16B at row (rbase+mi*16+l15),
    // col kb*64 + (kh*4+quad)*8  ->  Arow + mi*16*U_SZ + kb*64 + kh*32
    const bf16_t* Arow = Ap + (size_t)(rbase + l15) * U_SZ + quad * 8;

    // ---- B stage helper (into a parity) ----
    auto STAGE_B = [&](int ksrc, int par) {
        #pragma unroll
        for (int i = 0; i < 4; ++i) {
            int chunk = wave * 4 + i;
            LOAD_LDS16(Bp0 + (size_t)ksrc * 8192 + chunk * 512 + lane * 8,
                       &lsB[par][0][chunk * 512]);
            LOAD_LDS16(Bp1 + (size_t)ksrc * 8192 + chunk * 512 + lane * 8,
                       &lsB[par][1][chunk * 512]);
        }
    };

    // ---- pipeline fill: B(0) -> parity 0 ----
    STAGE_B(0, 0);

    // ---- prologue: x for my 128 rows (+ out write + praw-slot zero) ----
    if (tid < 128) {
        int row = G * 128 + tid;
        float x;
        if (t < SEQ) {
            x = inputs[row * SEQ + t];
        } else {
            float x1 = fmaxf(pr_read[row] + b1[0], 0.f);
            x = (t == SEQ) ? x1 : x1 * w2[0] + b2[0];
            if (p == 0) out[(size_t)row * TSTEPS + (t - SEQ)] = x;
        }
        lsX[tid] = x;
        if (p == 0) pr_zero[row] = 0.f;
    }

    // ---- K-loop: one barrier per kb; af direct-to-reg; B dbuf ----
    f32x4 acc[2][4][4] = {};

    #pragma clang loop unroll(disable)
    for (int kb = 0; kb < 16; ++kb) {
        // drains exactly stage_B(kb) (full-iteration cover) + barrier
        __syncthreads();

        // af(kb) FIRST (older than the B stage -> MFMA waits vmcnt(8))
        bf16x8 af[2][4];
        #pragma unroll
        for (int kh = 0; kh < 2; ++kh)
            #pragma unroll
            for (int mi = 0; mi < 4; ++mi)
                af[kh][mi] = *(const bf16x8*)(Arow + (size_t)mi * 16 * U_SZ
                                                   + kb * 64 + kh * 32);

        if (kb < 15) STAGE_B(kb + 1, (kb + 1) & 1);   // full-iter cover

        const bf16_t* lb = &lsB[kb & 1][0][0];
        bf16x8 bfr[2][2][4];
        #pragma unroll
        for (int kh = 0; kh < 2; ++kh) {
            int sw = (((kh * 4 + quad) ^ (lane & 7)) << 3);
            #pragma unroll
            for (int T = 0; T < 2; ++T)
                #pragma unroll
                for (int ni = 0; ni < 4; ++ni)
                    bfr[kh][T][ni] = *(const bf16x8*)
                        &lb[T * 8192 + (wc * 64 + ni * 16 + l15) * 64 + sw];
        }

        __builtin_amdgcn_s_setprio(1);
        #pragma unroll
        for (int kh = 0; kh < 2; ++kh)
            #pragma unroll
            for (int T = 0; T < 2; ++T)
                #pragma unroll
                for (int mi = 0; mi < 4; ++mi)
                    #pragma unroll
                    for (int ni = 0; ni < 4; ++ni)
                        acc[T][mi][ni] = __builtin_amdgcn_mfma_f32_16x16x32_bf16(
                            af[kh][mi], bfr[kh][T][ni], acc[T][mi][ni], 0, 0, 0);
        __builtin_amdgcn_s_setprio(0);
    }

    // ---- epilogue: gates, c RMW (global fp32), h write, pred partials ----
    int uu[2];
    uu[0] = (2 * p) * 32 + wc * 16 + l15;
    uu[1] = uu[0] + 32;
    float g_b[2][4], g_w[2][4], w1u[2];
    #pragma unroll
    for (int T = 0; T < 2; ++T) {
        #pragma unroll
        for (int g = 0; g < 4; ++g) {
            g_b[T][g] = bias[g * 1024 + uu[T]];
            g_w[T][g] = Wx[g * 1024 + uu[T]];
        }
        w1u[T] = w1[uu[T]];
    }
    const bool do_pred = (t >= SEQ - 1);

    #pragma unroll
    for (int mi = 0; mi < 4; ++mi) {
        #pragma unroll
        for (int r = 0; r < 4; ++r) {
            int rl   = rbase + mi * 16 + quad * 4 + r;
            int brow = G * 128 + rl;
            float xv = lsX[rl];
            float ps = 0.f;
            #pragma unroll
            for (int T = 0; T < 2; ++T) {
                float zi = acc[T][mi][0][r] + g_b[T][0] + xv * g_w[T][0];
                float zf = acc[T][mi][1][r] + g_b[T][1] + xv * g_w[T][1];
                float zg = acc[T][mi][2][r] + g_b[T][2] + xv * g_w[T][2];
                float zo = acc[T][mi][3][r] + g_b[T][3] + xv * g_w[T][3];
                float ig = fsig(zi), fg = fsig(zf);
                float gg = ftanh(zg), og = fsig(zo);
                size_t off = (size_t)brow * U_SZ + uu[T];
                float cn = fg * cst[off] + ig * gg;
                cst[off] = cn;
                float hv = og * ftanh(cn);
                hout[off] = (bf16_t)hv;
                ps += hv * w1u[T];
            }
            if (do_pred) {
                ps += __shfl_xor(ps, 1);
                ps += __shfl_xor(ps, 2);
                ps += __shfl_xor(ps, 4);
                ps += __shfl_xor(ps, 8);
                if (l15 == 0) atomicAdd(&pr_acc[brow], ps);
            }
        }
    }
}

// final output slot 199 from praw of step 203 (203 % 3 == 2)
__global__ void pred_final(const float* __restrict__ praw,
                           const float* __restrict__ b1,
                           const float* __restrict__ w2,
                           const float* __restrict__ b2,
                           float* __restrict__ out)
{
    int row = blockIdx.x * 256 + threadIdx.x;
    float x1 = fmaxf(praw[2 * B_SZ + row] + b1[0], 0.f);
    out[(size_t)row * TSTEPS + 199] = x1 * w2[0] + b2[0];
}

extern "C" void kernel_launch(void* const* d_in, const int* in_sizes, int n_in,
                              void* d_out, int out_size, void* d_ws, size_t ws_size,
                              hipStream_t stream) {
    const float* inputs = (const float*)d_in[0];   // [4096,5,1]
    const float* Wx     = (const float*)d_in[1];   // [1,4096]
    const float* R      = (const float*)d_in[2];   // [1024,4096]
    const float* bias   = (const float*)d_in[3];   // [4096]
    const float* w1     = (const float*)d_in[4];   // [1024,1]
    const float* b1     = (const float*)d_in[5];
    const float* w2     = (const float*)d_in[6];
    const float* b2     = (const float*)d_in[7];
    float* out = (float*)d_out;

    char* ws = (char*)d_ws;
    const size_t RP_BYTES = (size_t)32 * 131072 * 2;          // 8 MB
    const size_t H_BYTES  = (size_t)B_SZ * U_SZ * 2;          // 8 MB
    const size_t C_BYTES  = (size_t)B_SZ * U_SZ * 4;          // 16 MB
    bf16_t* Rp   = (bf16_t*)ws;                ws += RP_BYTES;
    bf16_t* h0   = (bf16_t*)ws;                ws += H_BYTES;
    bf16_t* h1   = (bf16_t*)ws;                ws += H_BYTES;
    float*  cbuf = (float*)ws;                 ws += C_BYTES;
    float*  praw = (float*)ws;                 ws += 3 * B_SZ * 4;
    bf16_t* hb[2] = {h0, h1};

    hipMemsetAsync(h0, 0, H_BYTES, stream);
    hipMemsetAsync(cbuf, 0, C_BYTES, stream);
    hipMemsetAsync(praw, 0, 3 * B_SZ * 4, stream);

    pack_R<<<16384, 256, 0, stream>>>(R, Rp);

    dim3 grid(16, 32);   // linear bid -> 2-D XCD tile decode in-kernel
    int cur = 0;
    for (int t = 0; t < STEPS; ++t) {
        lstm_step<<<grid, 256, 0, stream>>>(hb[cur], hb[1 - cur], cbuf, Rp,
                                            Wx, bias, w1, b1, w2, b2,
                                            inputs, praw, out, t);
        cur ^= 1;
    }
    pred_final<<<16, 256, 0, stream>>>(praw, b1, w2, b2, out);
}